// Round 12
// baseline (15277.492 us; speedup 1.0000x reference)
//
#include <hip/hip_runtime.h>
#include <hip/hip_bf16.h>
#include <cstdint>
#include <cstddef>

#define LOG2E 1.44269504088896340736f

using f32x4 = __attribute__((ext_vector_type(4))) float;
using s16x8 = __attribute__((ext_vector_type(8))) short;

static __device__ __forceinline__ float bf2f(unsigned short u) {
  union { unsigned int i; float f; } v; v.i = ((unsigned int)u) << 16; return v.f;
}
static __device__ __forceinline__ unsigned short f2bf(float f) {
  union { float f; unsigned int i; } v; v.f = f;
  unsigned int r = v.i + 0x7fffu + ((v.i >> 16) & 1u);
  return (unsigned short)(r >> 16);
}
static __device__ __forceinline__ float wredmax(float v) {
  #pragma unroll
  for (int m = 32; m > 0; m >>= 1) v = fmaxf(v, __shfl_xor(v, m, 64));
  return v;
}
static __device__ __forceinline__ float wredsum(float v) {
  #pragma unroll
  for (int m = 32; m > 0; m >>= 1) v += __shfl_xor(v, m, 64);
  return v;
}

// ---------------------------------------------------------------------------
// Transform kernel (unchanged, proven).
// ---------------------------------------------------------------------------
__global__ void ktrans(const float* __restrict__ W1, const float* __restrict__ b1,
                       const float* __restrict__ Wih_in, const float* __restrict__ bih,
                       const float* __restrict__ Whh, const float* __restrict__ bhh,
                       const float* __restrict__ Wfc, const float* __restrict__ bfc,
                       const float* __restrict__ yhist,
                       unsigned short* __restrict__ WB1, unsigned short* __restrict__ WBhh,
                       unsigned short* __restrict__ WB1e, float* __restrict__ b1s,
                       float* __restrict__ Wihs, float* __restrict__ gbias,
                       float* __restrict__ yh2)
{
  int idx = blockIdx.x * 256 + threadIdx.x;
  const float TS = 2.f * LOG2E;
  if (idx < 131072) {                       // WB1: (k,e')
    int k = idx >> 8, e = idx & 255;
    WB1[((k >> 3) * 256 + e) * 8 + (k & 7)] = f2bf(TS * W1[e * 768 + k]);
    return;
  }
  idx -= 131072;
  if (idx < 262144) {                       // WBhh: (k,j)
    int k = idx >> 10, j = idx & 1023;
    float sc = ((j >> 8) == 2) ? TS : -LOG2E;
    WBhh[((k >> 3) * 1024 + j) * 8 + (k & 7)] = f2bf(sc * Whh[j * 256 + k]);
    return;
  }
  idx -= 262144;
  if (idx < 65536) {                        // WB1e: (k,e'), x part
    int k = idx >> 8, e = idx & 255;
    WB1e[((k >> 3) * 256 + e) * 8 + (k & 7)] = f2bf(TS * W1[e * 768 + 512 + k]);
    return;
  }
  idx -= 65536;
  if (idx < 256) { b1s[idx] = TS * b1[idx]; return; }
  idx -= 256;
  if (idx < 2048) {                         // Wihs (j,o)
    int j = idx >> 1;
    float sc = ((j >> 8) == 2) ? TS : -LOG2E;
    Wihs[idx] = sc * Wih_in[idx];
    return;
  }
  idx -= 2048;
  if (idx < 1024) {
    int j = idx;
    float sc = ((j >> 8) == 2) ? TS : -LOG2E;
    gbias[j] = sc * (bih[j] + bhh[j]);
    return;
  }
  idx -= 1024;
  if (idx < 4096) {                         // yh2 (b,o)
    int bq = idx >> 1, o = idx & 1;
    float a = bfc[o];
    for (int t = 0; t < 64; ++t) a = fmaf(yhist[bq * 64 + t], Wfc[o * 320 + 256 + t], a);
    yh2[idx] = a;
    return;
  }
}

// ---------------------------------------------------------------------------
// Precompute kernel (unchanged, proven).
// ---------------------------------------------------------------------------
__global__ __launch_bounds__(256, 4) void kpre(
    const float* __restrict__ x, const unsigned short* __restrict__ WB1e,
    const float* __restrict__ Wfc,
    unsigned short* __restrict__ P, float* __restrict__ ey)
{
  __shared__ __align__(16) unsigned short xs[16384];
  const int bq = blockIdx.x;
  const int tid = threadIdx.x;
  const int w = tid >> 6, lane = tid & 63;
  const float* __restrict__ xb = x + (size_t)bq * 16384;

  #pragma unroll 4
  for (int it = 0; it < 16; ++it) {
    int idx = it * 256 + tid;
    float4 v = *(const float4*)(xb + (size_t)idx * 4);
    int t = idx >> 6, e0 = (idx & 63) * 4;
    unsigned long long pk = (unsigned long long)f2bf(v.x)
        | ((unsigned long long)f2bf(v.y) << 16)
        | ((unsigned long long)f2bf(v.z) << 32)
        | ((unsigned long long)f2bf(v.w) << 48);
    int ba = (t * 512 + e0 * 2) ^ ((t & 7) << 4);
    *(unsigned long long*)((char*)xs + ba) = pk;
  }
  __syncthreads();

  const int mt = w;
  const int fgrp = lane >> 4, fcol = lane & 15;
  const int trow = mt * 16 + fcol;
  s16x8 af[8];
  #pragma unroll
  for (int kb = 0; kb < 8; ++kb) {
    int e = kb * 32 + fgrp * 8;
    int ba = (trow * 512 + e * 2) ^ ((trow & 7) << 4);
    af[kb] = *(const s16x8*)((char*)xs + ba);
  }
  __syncthreads();

  unsigned short* __restrict__ Pst = xs;
  #pragma unroll
  for (int nt = 0; nt < 16; ++nt) {
    s16x8 bfr[8];
    #pragma unroll
    for (int kb = 0; kb < 8; ++kb)
      bfr[kb] = *(const s16x8*)&WB1e[(size_t)((kb * 4 + fgrp) * 256 + nt * 16 + fcol) * 8];
    f32x4 acc = {0.f, 0.f, 0.f, 0.f};
    #pragma unroll
    for (int kb = 0; kb < 8; ++kb)
      acc = __builtin_amdgcn_mfma_f32_16x16x32_bf16(af[kb], bfr[kb], acc, 0, 0, 0);
    const int ep = nt * 16 + fcol;
    #pragma unroll
    for (int r = 0; r < 4; ++r)
      Pst[(mt * 16 + fgrp * 4 + r) * 256 + ep] = f2bf(acc[r]);
  }
  __syncthreads();

  unsigned int* __restrict__ Pd = (unsigned int*)(P + (size_t)bq * 16384);
  #pragma unroll 4
  for (int d = tid; d < 8192; d += 256) {
    int f = d * 2;
    int ec = f >> 9, t = (f >> 3) & 63, i0 = f & 7;
    unsigned int lo = Pst[t * 256 + ec * 8 + i0];
    unsigned int hi = Pst[t * 256 + ec * 8 + i0 + 1];
    Pd[d] = lo | (hi << 16);
  }

  if (tid < 128) {
    int t = tid >> 1, o = tid & 1;
    float a = 0.f;
    const float* __restrict__ xr = xb + t * 256;
    const float* __restrict__ wr = Wfc + o * 320;
    #pragma unroll 4
    for (int e = 0; e < 256; ++e) a = fmaf(xr[e], wr[e], a);
    ey[((size_t)bq * 64 + t) * 2 + o] = a;
  }
}

// ---------------------------------------------------------------------------
// Recurrence v12: ALL-LDS P, R5 idiom. 512 blocks x 4 rows, 256 thr / 4 waves,
// wave = row end-to-end. Zero per-step global reads except weights (L2-hot).
// VGPR budget 256 (65536/256), demand ~170 -> no spill. 3 barriers/step.
// ---------------------------------------------------------------------------
#define SIG(X) __builtin_amdgcn_rcpf(1.f + __builtin_amdgcn_exp2f(X))
#define MFMA(A, B, C) __builtin_amdgcn_mfma_f32_16x16x32_bf16((A), (B), (C), 0, 0, 0)

// score chunk EC (0..31) from LDS; accumulates a0..a3
#define SCCH(EC) do { \
  const s16x8 pv_ = *(const s16x8*)&Plds[wv][(EC)][lane][0]; \
  const float4 qa_ = *(const float4*)(qrow + (EC) * 8); \
  const float4 qb_ = *(const float4*)(qrow + (EC) * 8 + 4); \
  const float4 wa_ = *(const float4*)(w2f + (EC) * 8); \
  const float4 wb_ = *(const float4*)(w2f + (EC) * 8 + 4); \
  a0 = fmaf(wa_.x, SIG(bf2f((unsigned short)pv_[0]) + qa_.x), a0); \
  a1 = fmaf(wa_.y, SIG(bf2f((unsigned short)pv_[1]) + qa_.y), a1); \
  a2 = fmaf(wa_.z, SIG(bf2f((unsigned short)pv_[2]) + qa_.z), a2); \
  a3 = fmaf(wa_.w, SIG(bf2f((unsigned short)pv_[3]) + qa_.w), a3); \
  a0 = fmaf(wb_.x, SIG(bf2f((unsigned short)pv_[4]) + qb_.x), a0); \
  a1 = fmaf(wb_.y, SIG(bf2f((unsigned short)pv_[5]) + qb_.y), a1); \
  a2 = fmaf(wb_.z, SIG(bf2f((unsigned short)pv_[6]) + qb_.z), a2); \
  a3 = fmaf(wb_.w, SIG(bf2f((unsigned short)pv_[7]) + qb_.w), a3); \
} while (0)

__global__ __launch_bounds__(256) void krecur(
    const float* __restrict__ x, const float* __restrict__ w2g,
    const unsigned short* __restrict__ WB1, const unsigned short* __restrict__ WBhh,
    const float* __restrict__ Wihs, const float* __restrict__ gbias,
    const float* __restrict__ b1s, const float* __restrict__ yh2,
    const float* __restrict__ ey, const unsigned short* __restrict__ P,
    const float* __restrict__ Wfin, const float* __restrict__ bfin,
    float* __restrict__ out)
{
  __shared__ __align__(16) unsigned short Plds[4][32][64][8]; // 128 KB; ctx alias at end
  __shared__ __align__(16) unsigned short hcA[2048];          // 4 KB [k>>3][row4][k&7]
  __shared__ __align__(16) float qf[4][256];                  // 4 KB q; h(f32) stash s63
  __shared__ __align__(16) float gl[4][1024];                 // 16 KB gates
  __shared__ __align__(16) float w2f[256];                    // 1 KB
  __shared__ __align__(16) float scAl[4][64];                 // 1 KB
  __shared__ float yt[4][2];                                  // ~157.7 KB total

  const int tid = threadIdx.x;
  const int wv = tid >> 6, lane = tid & 63;
  const int gbase = blockIdx.x * 4;
  const int gb = gbase + wv;            // wave = row

  for (int i = tid; i < 2048; i += 256) hcA[i] = 0;
  w2f[tid] = w2g[tid];
  for (int i = tid; i < 8192; i += 256) {
    int rw = i >> 11, rem = i & 2047;   // rem = ec*64 + t
    *(s16x8*)&Plds[rw][rem >> 6][rem & 63][0] =
        *(const s16x8*)(P + (size_t)(gbase + rw) * 16384 + (size_t)rem * 8);
  }

  const int frow = lane & 3;            // A-frag batch row (rows 4..15 dup)
  const int fgrp = lane >> 4;
  const int fcol = lane & 15;

  const float2 eyv = *(const float2*)(ey + ((size_t)gb * 64 + lane) * 2);
  const float yh0 = yh2[gb * 2], yh1 = yh2[gb * 2 + 1];
  const float b1r0 = b1s[wv * 64 + fcol];
  const float b1r1 = b1s[wv * 64 + 16 + fcol];
  const float b1r2 = b1s[wv * 64 + 32 + fcol];
  const float b1r3 = b1s[wv * 64 + 48 + fcol];

  const int j0 = lane * 4;              // this thread's 4 LSTM cells (row wv)
  const float4 wiIa = *(const float4*)&Wihs[2 * j0];
  const float4 wiIb = *(const float4*)&Wihs[2 * j0 + 4];
  const float4 wiFa = *(const float4*)&Wihs[2 * (256 + j0)];
  const float4 wiFb = *(const float4*)&Wihs[2 * (256 + j0) + 4];
  const float4 wiGa = *(const float4*)&Wihs[2 * (512 + j0)];
  const float4 wiGb = *(const float4*)&Wihs[2 * (512 + j0) + 4];
  const float4 wiOa = *(const float4*)&Wihs[2 * (768 + j0)];
  const float4 wiOb = *(const float4*)&Wihs[2 * (768 + j0) + 4];

  float c0 = 0.f, c1 = 0.f, c2 = 0.f, c3 = 0.f;

  __syncthreads();

  for (int s = 0; s < 64; ++s) {
    // ---- hoist A fragments (hc state) once per step: 16 x s16x8 ----
    s16x8 afr[16];
    #pragma unroll
    for (int kb = 0; kb < 16; ++kb)
      afr[kb] = *(const s16x8*)&hcA[((kb * 4 + fgrp) * 4 + frow) * 8];

    // ---- phase1: q cols [wv*64, +64), K=512 over [h|c] ----
    {
      const int cb = wv * 64 + fcol;
      f32x4 q0 = {0.f,0.f,0.f,0.f}, q1 = {0.f,0.f,0.f,0.f};
      f32x4 q2 = {0.f,0.f,0.f,0.f}, q3 = {0.f,0.f,0.f,0.f};
      #pragma unroll
      for (int kb = 0; kb < 16; ++kb) {
        const size_t ko = (size_t)(kb * 4 + fgrp) * 256;
        const s16x8 B0 = *(const s16x8*)&WB1[(ko + cb) * 8];
        const s16x8 B1 = *(const s16x8*)&WB1[(ko + cb + 16) * 8];
        const s16x8 B2 = *(const s16x8*)&WB1[(ko + cb + 32) * 8];
        const s16x8 B3 = *(const s16x8*)&WB1[(ko + cb + 48) * 8];
        q0 = MFMA(afr[kb], B0, q0);
        q1 = MFMA(afr[kb], B1, q1);
        q2 = MFMA(afr[kb], B2, q2);
        q3 = MFMA(afr[kb], B3, q3);
      }
      if (fgrp == 0) {                  // D rows 0..3 = true rows
        #pragma unroll
        for (int r = 0; r < 4; ++r) {
          qf[r][cb]      = q0[r] + b1r0;
          qf[r][cb + 16] = q1[r] + b1r1;
          qf[r][cb + 32] = q2[r] + b1r2;
          qf[r][cb + 48] = q3[r] + b1r3;
        }
      }
    }
    __syncthreads();                                   // B1: qf ready

    // ---- phase2: 16 gate-units (WBhh L2 stream) + 2 score chunks each ----
    float a0 = 0.f, a1 = 0.f, a2 = 0.f, a3 = 0.f;
    const float* __restrict__ qrow = &qf[wv][0];
    #pragma unroll
    for (int u = 0; u < 16; ++u) {
      const int j = wv * 256 + u * 16 + fcol;
      const float gbj = gbias[j];
      f32x4 G = {gbj, gbj, gbj, gbj};
      const size_t jb = (size_t)j * 8;
      {
        const s16x8 B0 = *(const s16x8*)&WBhh[jb + (size_t)(0 * 4 + fgrp) * 8192];
        const s16x8 B1 = *(const s16x8*)&WBhh[jb + (size_t)(1 * 4 + fgrp) * 8192];
        const s16x8 B2 = *(const s16x8*)&WBhh[jb + (size_t)(2 * 4 + fgrp) * 8192];
        const s16x8 B3 = *(const s16x8*)&WBhh[jb + (size_t)(3 * 4 + fgrp) * 8192];
        SCCH(2 * u);
        G = MFMA(afr[0], B0, G);
        G = MFMA(afr[1], B1, G);
        G = MFMA(afr[2], B2, G);
        G = MFMA(afr[3], B3, G);
      }
      {
        const s16x8 B4 = *(const s16x8*)&WBhh[jb + (size_t)(4 * 4 + fgrp) * 8192];
        const s16x8 B5 = *(const s16x8*)&WBhh[jb + (size_t)(5 * 4 + fgrp) * 8192];
        const s16x8 B6 = *(const s16x8*)&WBhh[jb + (size_t)(6 * 4 + fgrp) * 8192];
        const s16x8 B7 = *(const s16x8*)&WBhh[jb + (size_t)(7 * 4 + fgrp) * 8192];
        SCCH(2 * u + 1);
        G = MFMA(afr[4], B4, G);
        G = MFMA(afr[5], B5, G);
        G = MFMA(afr[6], B6, G);
        G = MFMA(afr[7], B7, G);
      }
      if (fgrp == 0) {
        #pragma unroll
        for (int r = 0; r < 4; ++r) gl[r][j] = G[r];
      }
    }

    // softmax + ytilde (wave = row, lane = t)
    {
      float sc = -2.f * ((a0 + a1) + (a2 + a3));
      float mx = wredmax(sc);
      float e_t = __builtin_amdgcn_exp2f((sc - mx) * LOG2E);
      float sm = wredsum(e_t);
      float alpha = e_t * __builtin_amdgcn_rcpf(sm);
      if (s == 63) scAl[wv][lane] = alpha;
      float y0 = wredsum(alpha * eyv.x);
      float y1 = wredsum(alpha * eyv.y);
      if (lane == 0) { yt[wv][0] = y0 + yh0; yt[wv][1] = y1 + yh1; }
    }
    __syncthreads();                                   // B2: gl, yt ready

    // ---- phase3: pointwise, 4 cells j0..j0+3 of row wv ----
    {
      const float y0 = yt[wv][0], y1 = yt[wv][1];
      const float4 gI = *(const float4*)&gl[wv][j0];
      const float4 gF = *(const float4*)&gl[wv][256 + j0];
      const float4 gG = *(const float4*)&gl[wv][512 + j0];
      const float4 gO = *(const float4*)&gl[wv][768 + j0];
      const float gi0 = gI.x + fmaf(wiIa.x, y0, wiIa.y * y1);
      const float gf0 = gF.x + fmaf(wiFa.x, y0, wiFa.y * y1);
      const float gg0 = gG.x + fmaf(wiGa.x, y0, wiGa.y * y1);
      const float go0 = gO.x + fmaf(wiOa.x, y0, wiOa.y * y1);
      const float gi1 = gI.y + fmaf(wiIa.z, y0, wiIa.w * y1);
      const float gf1 = gF.y + fmaf(wiFa.z, y0, wiFa.w * y1);
      const float gg1 = gG.y + fmaf(wiGa.z, y0, wiGa.w * y1);
      const float go1 = gO.y + fmaf(wiOa.z, y0, wiOa.w * y1);
      const float gi2 = gI.z + fmaf(wiIb.x, y0, wiIb.y * y1);
      const float gf2 = gF.z + fmaf(wiFb.x, y0, wiFb.y * y1);
      const float gg2 = gG.z + fmaf(wiGb.x, y0, wiGb.y * y1);
      const float go2 = gO.z + fmaf(wiOb.x, y0, wiOb.y * y1);
      const float gi3 = gI.w + fmaf(wiIb.z, y0, wiIb.w * y1);
      const float gf3 = gF.w + fmaf(wiFb.z, y0, wiFb.w * y1);
      const float gg3 = gG.w + fmaf(wiGb.z, y0, wiGb.w * y1);
      const float go3 = gO.w + fmaf(wiOb.z, y0, wiOb.w * y1);

      const float cn0 = SIG(gf0) * c0 + SIG(gi0) * (1.f - 2.f * SIG(gg0));
      const float cn1 = SIG(gf1) * c1 + SIG(gi1) * (1.f - 2.f * SIG(gg1));
      const float cn2 = SIG(gf2) * c2 + SIG(gi2) * (1.f - 2.f * SIG(gg2));
      const float cn3 = SIG(gf3) * c3 + SIG(gi3) * (1.f - 2.f * SIG(gg3));
      c0 = cn0; c1 = cn1; c2 = cn2; c3 = cn3;
      const float h0 = SIG(go0) * (1.f - 2.f * SIG(2.f * LOG2E * cn0));
      const float h1 = SIG(go1) * (1.f - 2.f * SIG(2.f * LOG2E * cn1));
      const float h2 = SIG(go2) * (1.f - 2.f * SIG(2.f * LOG2E * cn2));
      const float h3 = SIG(go3) * (1.f - 2.f * SIG(2.f * LOG2E * cn3));

      const int kg = j0 >> 3, off = j0 & 7;
      uint2 hp, cp;
      hp.x = (unsigned int)f2bf(h0) | ((unsigned int)f2bf(h1) << 16);
      hp.y = (unsigned int)f2bf(h2) | ((unsigned int)f2bf(h3) << 16);
      cp.x = (unsigned int)f2bf(cn0) | ((unsigned int)f2bf(cn1) << 16);
      cp.y = (unsigned int)f2bf(cn2) | ((unsigned int)f2bf(cn3) << 16);
      *(uint2*)&hcA[(kg * 4 + wv) * 8 + off] = hp;
      *(uint2*)&hcA[((32 + kg) * 4 + wv) * 8 + off] = cp;
      if (s == 63) *(float4*)&qf[wv][j0] = make_float4(h0, h1, h2, h3);
    }
    __syncthreads();                                   // B3: hcA ready
  }

  // ---- ctx[wv][e] = sum_t alpha_t * x[gb,t,e]  (into Plds alias) ----
  {
    float* __restrict__ ctxS = (float*)Plds;
    const int e0 = lane * 4;
    float A0 = 0.f, A1 = 0.f, A2 = 0.f, A3 = 0.f;
    const float* __restrict__ xr = x + (size_t)gb * 16384 + e0;
    #pragma unroll 8
    for (int t = 0; t < 64; ++t) {
      const float al = scAl[wv][t];
      const float4 xv = *(const float4*)(xr + (size_t)t * 256);
      A0 = fmaf(al, xv.x, A0);
      A1 = fmaf(al, xv.y, A1);
      A2 = fmaf(al, xv.z, A2);
      A3 = fmaf(al, xv.w, A3);
    }
    *(float4*)&ctxS[wv * 256 + e0] = make_float4(A0, A1, A2, A3);
  }
  __syncthreads();

  // ---- final: out = [h, ctx] @ W_final.T + b_final (wave = row) ----
  {
    const float* __restrict__ ctxS = (const float*)Plds;
    float o0 = 0.f, o1 = 0.f;
    #pragma unroll
    for (int kk = 0; kk < 8; ++kk) {
      const int k = kk * 64 + lane;
      const float v = (k < 256) ? qf[wv][k] : ctxS[wv * 256 + (k - 256)];
      o0 = fmaf(v, Wfin[k], o0);
      o1 = fmaf(v, Wfin[512 + k], o1);
    }
    o0 = wredsum(o0);
    o1 = wredsum(o1);
    if (lane == 0) {
      out[gb * 2 + 0] = o0 + bfin[0];
      out[gb * 2 + 1] = o1 + bfin[1];
    }
  }
}

// ---------------------------------------------------------------------------
extern "C" void kernel_launch(void* const* d_in, const int* in_sizes, int n_in,
                              void* d_out, int out_size, void* d_ws, size_t ws_size,
                              hipStream_t stream) {
  const float* x    = (const float*)d_in[0];
  const float* yh   = (const float*)d_in[1];
  const float* W1   = (const float*)d_in[2];
  const float* b1   = (const float*)d_in[3];
  const float* w2   = (const float*)d_in[4];
  // d_in[5] = b2: softmax-invariant -> unused
  const float* Wih  = (const float*)d_in[6];
  const float* bih  = (const float*)d_in[7];
  const float* Whh  = (const float*)d_in[8];
  const float* bhh  = (const float*)d_in[9];
  const float* Wfc  = (const float*)d_in[10];
  const float* bfc  = (const float*)d_in[11];
  const float* Wfin = (const float*)d_in[12];
  const float* bfin = (const float*)d_in[13];

  char* ws = (char*)d_ws;
  unsigned short* P    = (unsigned short*)(ws + 0);          // 67,108,864 B
  unsigned short* WB1  = (unsigned short*)(ws + 67108864);   //    262,144 B
  unsigned short* WBhh = (unsigned short*)(ws + 67371008);   //    524,288 B
  unsigned short* WB1e = (unsigned short*)(ws + 67895296);   //    131,072 B
  float* b1s   = (float*)(ws + 68026368);                    //      1,024 B
  float* Wihs  = (float*)(ws + 68027392);                    //      8,192 B
  float* gbias = (float*)(ws + 68035584);                    //      4,096 B
  float* yh2   = (float*)(ws + 68039680);                    //     16,384 B
  float* ey    = (float*)(ws + 68056064);                    //  1,048,576 B -> 69,104,640 total

  ktrans<<<1821, 256, 0, stream>>>(W1, b1, Wih, bih, Whh, bhh, Wfc, bfc, yh,
                                   WB1, WBhh, WB1e, b1s, Wihs, gbias, yh2);
  kpre<<<2048, 256, 0, stream>>>(x, WB1e, Wfc, P, ey);
  krecur<<<512, 256, 0, stream>>>(x, w2, WB1, WBhh, Wihs, gbias, b1s, yh2, ey, P,
                                  Wfin, bfin, (float*)d_out);
}